// Round 2
// baseline (216.707 us; speedup 1.0000x reference)
//
#include <hip/hip_runtime.h>

// Linformer head, MFMA bf16-split rewrite. B=16, S=4096, D=64, KP=256.
// d_in: Q, K, V [B,S,D] f32; E_w,F_w [KP,S] f32; E_b,F_b [KP] f32
// d_out: out[B,S,D] ++ attn[B,S,KP] f32
// R1 change: attn kernel Qf/Pl LDS union (Qf dead after score loop; one barrier
// added) -> LDS 50176->33792 B -> 4 blocks/CU (grid 1024 = exactly 4/CU, no
// tail batch). Attacks measured latency-bound regime (Mfma 4.5%, VALU 11%,
// HBM 18%, Occ 23.5%).

#define B_  16
#define S_  4096
#define D_  64
#define KP_ 256

typedef short v8s __attribute__((ext_vector_type(8)));
typedef float v4f __attribute__((ext_vector_type(4)));

__device__ __forceinline__ short f2bf(float x) {        // RNE f32 -> bf16
    union { float f; unsigned u; } v; v.f = x;
    unsigned r = v.u + 0x7FFFu + ((v.u >> 16) & 1u);
    return (short)(r >> 16);
}
__device__ __forceinline__ float bf2f(short h) {
    union { float f; unsigned u; } v; v.u = ((unsigned)(unsigned short)h) << 16;
    return v.f;
}

// ---------------------------------------------------------------------------
// Kernel 1: W fp32 -> bf16 hi/lo planes. grid (1024, 2) x 256.
// ---------------------------------------------------------------------------
__global__ __launch_bounds__(256)
void wcvt_kernel(const float* __restrict__ E_w, const float* __restrict__ F_w,
                 short* __restrict__ Whi, short* __restrict__ Wlo)
{
    const int p = blockIdx.y;
    const float* W = p ? F_w : E_w;
    const size_t i4 = (size_t)blockIdx.x * 256 + threadIdx.x;   // float4 idx
    float4 v = ((const float4*)W)[i4];
    short4 h, lo;
    h.x = f2bf(v.x); lo.x = f2bf(v.x - bf2f(h.x));
    h.y = f2bf(v.y); lo.y = f2bf(v.y - bf2f(h.y));
    h.z = f2bf(v.z); lo.z = f2bf(v.z - bf2f(h.z));
    h.w = f2bf(v.w); lo.w = f2bf(v.w - bf2f(h.w));
    const size_t o = (size_t)p * (KP_ * S_) + i4 * 4;
    *(short4*)(Whi + o) = h;
    *(short4*)(Wlo + o) = lo;
}

// ---------------------------------------------------------------------------
// Kernel 2: projections via MFMA, split-S partials.
// grid (sc 8, p 2, b 16) x 512 thr (8 waves). 1 block/CU, 2 waves/SIMD.
// p=0: PpartK[sc][b][k 256][d 64] += E_w-chunk @ K-chunk   (C[k,d]: A=W, B=src)
// p=1: PpartV[sc][b][d 64][k 256] += (F_w-chunk @ V-chunk)^T (C'[d,k]: A=src, B=W)
// src staged per 32-s step into MFMA-fragment-order LDS (hi/lo), dbl-buffered.
// W fragments read straight from bf16 planes (16B contiguous per lane).
// ---------------------------------------------------------------------------
__global__ __launch_bounds__(512, 2)
void proj_mfma_kernel(const float* __restrict__ Kg, const float* __restrict__ Vg,
                      const short* __restrict__ Whi, const short* __restrict__ Wlo,
                      float* __restrict__ PpartK, float* __restrict__ PpartV)
{
    const int sc = blockIdx.x;     // s-chunk of 512
    const int p  = blockIdx.y;     // 0 -> Kp, 1 -> Vp
    const int b  = blockIdx.z;

    const float* src = (p ? Vg : Kg) + ((size_t)b * S_ + sc * 512) * D_;
    const short* Wh = Whi + (size_t)p * KP_ * S_ + sc * 512;
    const short* Wl = Wlo + (size_t)p * KP_ * S_ + sc * 512;

    __shared__ __align__(16) short Af[2][2][4][512];  // [buf][plane][mt=d/16][fraglane*8] 16KB

    const int t  = threadIdx.x;
    const int wv = t >> 6;
    const int l  = t & 63;

    v4f acc[2][4];
#pragma unroll
    for (int i = 0; i < 2; ++i)
#pragma unroll
        for (int m = 0; m < 4; ++m) acc[i][m] = (v4f){0.f, 0.f, 0.f, 0.f};

    // staging role (threads 0..255): thread owns (d = sd, s-oct = soct) -> one frag-lane
    const bool do_stage = (t < 256);
    const int sd   = t & 63;
    const int soct = (t >> 6) & 3;
    const int smt  = sd >> 4;
    const int sfl  = (sd & 15) + soct * 16;

    float g[8];
    if (do_stage) {
        const float* sp = src + (size_t)(soct * 8) * D_ + sd;
#pragma unroll
        for (int j = 0; j < 8; ++j) g[j] = sp[(size_t)j * D_];
        v8s hi, lo;
#pragma unroll
        for (int j = 0; j < 8; ++j) { short h = f2bf(g[j]); hi[j] = h; lo[j] = f2bf(g[j] - bf2f(h)); }
        *(v8s*)&Af[0][0][smt][sfl * 8] = hi;
        *(v8s*)&Af[0][1][smt][sfl * 8] = lo;
    }
    __syncthreads();

    const int krow0 = wv * 32;   // wave's 32-wide k range

    for (int st = 0; st < 16; ++st) {
        const int cur = st & 1;
        if (st + 1 < 16 && do_stage) {      // issue next-step loads (waited at cvt below)
            const float* sp = src + (size_t)((st + 1) * 32 + soct * 8) * D_ + sd;
#pragma unroll
            for (int j = 0; j < 8; ++j) g[j] = sp[(size_t)j * D_];
        }
        // W fragments (global bf16 planes, contiguous 16B per lane)
        v8s wh[2], wl2[2];
#pragma unroll
        for (int i = 0; i < 2; ++i) {
            size_t off = (size_t)(krow0 + i * 16 + (l & 15)) * S_ + st * 32 + (l >> 4) * 8;
            wh[i]  = *(const v8s*)(Wh + off);
            wl2[i] = *(const v8s*)(Wl + off);
        }
        // src fragments (LDS, fragment order: lane reads its own 16B)
        v8s sh[4], sl[4];
#pragma unroll
        for (int m = 0; m < 4; ++m) {
            sh[m] = *(const v8s*)&Af[cur][0][m][l * 8];
            sl[m] = *(const v8s*)&Af[cur][1][m][l * 8];
        }
        if (p == 0) {       // C[k,d] = W @ src : A=W, B=src
#pragma unroll
            for (int i = 0; i < 2; ++i)
#pragma unroll
                for (int m = 0; m < 4; ++m) {
                    acc[i][m] = __builtin_amdgcn_mfma_f32_16x16x32_bf16(wh[i],  sh[m], acc[i][m], 0, 0, 0);
                    acc[i][m] = __builtin_amdgcn_mfma_f32_16x16x32_bf16(wh[i],  sl[m], acc[i][m], 0, 0, 0);
                    acc[i][m] = __builtin_amdgcn_mfma_f32_16x16x32_bf16(wl2[i], sh[m], acc[i][m], 0, 0, 0);
                }
        } else {            // C'[d,k] = src^T @ W^T : A=src, B=W
#pragma unroll
            for (int i = 0; i < 2; ++i)
#pragma unroll
                for (int m = 0; m < 4; ++m) {
                    acc[i][m] = __builtin_amdgcn_mfma_f32_16x16x32_bf16(sh[m], wh[i],  acc[i][m], 0, 0, 0);
                    acc[i][m] = __builtin_amdgcn_mfma_f32_16x16x32_bf16(sl[m], wh[i],  acc[i][m], 0, 0, 0);
                    acc[i][m] = __builtin_amdgcn_mfma_f32_16x16x32_bf16(sh[m], wl2[i], acc[i][m], 0, 0, 0);
                }
        }
        if (st + 1 < 16 && do_stage) {      // convert + write next buffer
            v8s hi, lo;
#pragma unroll
            for (int j = 0; j < 8; ++j) { short h = f2bf(g[j]); hi[j] = h; lo[j] = f2bf(g[j] - bf2f(h)); }
            *(v8s*)&Af[cur ^ 1][0][smt][sfl * 8] = hi;
            *(v8s*)&Af[cur ^ 1][1][smt][sfl * 8] = lo;
        }
        __syncthreads();
    }

    if (p == 0) {
        float* outp = PpartK + ((size_t)sc * B_ + b) * (KP_ * D_);
#pragma unroll
        for (int i = 0; i < 2; ++i)
#pragma unroll
            for (int m = 0; m < 4; ++m)
#pragma unroll
                for (int r = 0; r < 4; ++r) {
                    int k = krow0 + i * 16 + (l >> 4) * 4 + r;
                    int d = m * 16 + (l & 15);
                    outp[(size_t)k * D_ + d] = acc[i][m][r];
                }
    } else {
        float* outp = PpartV + ((size_t)sc * B_ + b) * (KP_ * D_);
#pragma unroll
        for (int i = 0; i < 2; ++i)
#pragma unroll
            for (int m = 0; m < 4; ++m)
#pragma unroll
                for (int r = 0; r < 4; ++r) {
                    int d = m * 16 + (l >> 4) * 4 + r;
                    int k = krow0 + i * 16 + (l & 15);
                    outp[(size_t)d * KP_ + k] = acc[i][m][r];
                }
    }
}

// ---------------------------------------------------------------------------
// Kernel 3: reduce partials + bias -> bf16 planes.
// Kp (k-major [b][k][d]) -> hi+lo; Vp (d-major [b][d][k]) -> hi. grid 512x256.
// ---------------------------------------------------------------------------
__global__ __launch_bounds__(256)
void reduce_kernel(const float* __restrict__ PpartK, const float* __restrict__ PpartV,
                   const float* __restrict__ E_b, const float* __restrict__ F_b,
                   short* __restrict__ Kp_hi, short* __restrict__ Kp_lo,
                   short* __restrict__ Vp_hi)
{
    const int j    = blockIdx.x * 256 + threadIdx.x;   // 0..131071
    const int side = j >> 16;                          // block-uniform
    const int i4   = j & 65535;
    const int flat = i4 * 4;                           // b*16384 + dk
    const int b    = flat >> 14;
    const int dk   = flat & 16383;

    if (side == 0) {
        float4 a = make_float4(0.f, 0.f, 0.f, 0.f);
#pragma unroll
        for (int sc = 0; sc < 8; ++sc) {
            float4 v = *(const float4*)(PpartK + ((size_t)sc * B_ + b) * (KP_ * D_) + dk);
            a.x += v.x; a.y += v.y; a.z += v.z; a.w += v.w;
        }
        float be = E_b[dk >> 6];                       // k = dk/64 (d contiguous)
        a.x += be; a.y += be; a.z += be; a.w += be;
        short4 h, lo;
        h.x = f2bf(a.x); lo.x = f2bf(a.x - bf2f(h.x));
        h.y = f2bf(a.y); lo.y = f2bf(a.y - bf2f(h.y));
        h.z = f2bf(a.z); lo.z = f2bf(a.z - bf2f(h.z));
        h.w = f2bf(a.w); lo.w = f2bf(a.w - bf2f(h.w));
        *(short4*)(Kp_hi + (size_t)b * 16384 + dk) = h;
        *(short4*)(Kp_lo + (size_t)b * 16384 + dk) = lo;
    } else {
        float4 a = make_float4(0.f, 0.f, 0.f, 0.f);
#pragma unroll
        for (int sc = 0; sc < 8; ++sc) {
            float4 v = *(const float4*)(PpartV + ((size_t)sc * B_ + b) * (KP_ * D_) + dk);
            a.x += v.x; a.y += v.y; a.z += v.z; a.w += v.w;
        }
        float4 bf = *(const float4*)(F_b + (dk & 255));   // k contiguous
        a.x += bf.x; a.y += bf.y; a.z += bf.z; a.w += bf.w;
        short4 h;
        h.x = f2bf(a.x); h.y = f2bf(a.y); h.z = f2bf(a.z); h.w = f2bf(a.w);
        *(short4*)(Vp_hi + (size_t)b * 16384 + dk) = h;
    }
}

// ---------------------------------------------------------------------------
// Kernel 4: scores -> softmax -> attn write -> out, all MFMA.
// grid (64 st, 16 b) x 256 thr (4 waves); wave owns 16 s-rows.
// LDS: union(Qf 16KB, Pl 33KB) = 33792 B -> 4 blocks/CU (was 3 + tail).
// Qf is dead after the score loop (each wave reads only its own mt=wv slice);
// one __syncthreads() separates last Qf read from first Pl write.
// ---------------------------------------------------------------------------
__global__ __launch_bounds__(256, 4)
void attn_mfma_kernel(const float* __restrict__ Qg,
                      const short* __restrict__ Kp_hi, const short* __restrict__ Kp_lo,
                      const short* __restrict__ Vp_hi,
                      float* __restrict__ attn_out, float* __restrict__ outg)
{
    const int st = blockIdx.x;
    const int b  = blockIdx.y;
    const int t  = threadIdx.x;
    const int wv = t >> 6;
    const int l  = t & 63;

    __shared__ __align__(16) short smem[64 * 264];     // union: Qf (first 8192) / Pl
    short (*Qf)[2][4][512] = (short (*)[2][4][512])smem;   // [kd][plane][mt][fraglane*8]
    short* Pl = smem;                                  // attn tile, pitch 264

    {   // stage Q fragments (hi/lo)
        const int s    = t & 63;
        const int doct = t >> 6;
        const float* qrow = Qg + ((size_t)b * S_ + st * 64 + s) * D_;
        const int mt = s >> 4, fl = (s & 15) + doct * 16;
#pragma unroll
        for (int kd = 0; kd < 2; ++kd) {
            float4 v0 = *(const float4*)(qrow + kd * 32 + doct * 8);
            float4 v1 = *(const float4*)(qrow + kd * 32 + doct * 8 + 4);
            float gq[8] = {v0.x, v0.y, v0.z, v0.w, v1.x, v1.y, v1.z, v1.w};
            v8s hi, lo;
#pragma unroll
            for (int jj = 0; jj < 8; ++jj) { short h = f2bf(gq[jj]); hi[jj] = h; lo[jj] = f2bf(gq[jj] - bf2f(h)); }
            *(v8s*)&Qf[kd][0][mt][fl * 8] = hi;
            *(v8s*)&Qf[kd][1][mt][fl * 8] = lo;
        }
    }
    __syncthreads();

    // scores: C2[16 s x 256 k], 3-term split
    v4f acc2[16];
#pragma unroll
    for (int nt = 0; nt < 16; ++nt) acc2[nt] = (v4f){0.f, 0.f, 0.f, 0.f};
    const size_t kb = (size_t)b * (KP_ * D_);
#pragma unroll
    for (int kd = 0; kd < 2; ++kd) {
        v8s Ah = *(const v8s*)&Qf[kd][0][wv][l * 8];
        v8s Al = *(const v8s*)&Qf[kd][1][wv][l * 8];
#pragma unroll
        for (int nt = 0; nt < 16; ++nt) {
            size_t off = kb + (size_t)(nt * 16 + (l & 15)) * D_ + kd * 32 + (l >> 4) * 8;
            v8s Bh = *(const v8s*)(Kp_hi + off);
            v8s Bl = *(const v8s*)(Kp_lo + off);
            acc2[nt] = __builtin_amdgcn_mfma_f32_16x16x32_bf16(Ah, Bh, acc2[nt], 0, 0, 0);
            acc2[nt] = __builtin_amdgcn_mfma_f32_16x16x32_bf16(Al, Bh, acc2[nt], 0, 0, 0);
            acc2[nt] = __builtin_amdgcn_mfma_f32_16x16x32_bf16(Ah, Bl, acc2[nt], 0, 0, 0);
        }
    }
    __syncthreads();   // Qf dead from here; Pl may now reuse the LDS

    // softmax per row (C layout: row = wv*16 + (l>>4)*4 + r, col = nt*16 + (l&15))
    const float scale = 0.125f;   // 1/sqrt(64)
    float* attn_b = attn_out + ((size_t)b * S_ + st * 64) * KP_;
#pragma unroll
    for (int r = 0; r < 4; ++r) {
        float m = -3.4e38f;
#pragma unroll
        for (int nt = 0; nt < 16; ++nt) m = fmaxf(m, acc2[nt][r]);
        m = fmaxf(m, __shfl_xor(m, 1));
        m = fmaxf(m, __shfl_xor(m, 2));
        m = fmaxf(m, __shfl_xor(m, 4));
        m = fmaxf(m, __shfl_xor(m, 8));
        float sum = 0.f;
#pragma unroll
        for (int nt = 0; nt < 16; ++nt) {
            float e = __expf((acc2[nt][r] - m) * scale);
            acc2[nt][r] = e; sum += e;
        }
        sum += __shfl_xor(sum, 1);
        sum += __shfl_xor(sum, 2);
        sum += __shfl_xor(sum, 4);
        sum += __shfl_xor(sum, 8);
        const float inv = 1.f / sum;
        const int s_loc = wv * 16 + (l >> 4) * 4 + r;
#pragma unroll
        for (int nt = 0; nt < 16; ++nt) {
            float pv = acc2[nt][r] * inv;
            attn_b[(size_t)s_loc * KP_ + nt * 16 + (l & 15)] = pv;
            Pl[s_loc * 264 + nt * 16 + (l & 15)] = f2bf(pv);
        }
    }
    // PV: rows wv*16..+16 were written by this wave only -> no barrier needed
    v4f acc3[4];
#pragma unroll
    for (int nt = 0; nt < 4; ++nt) acc3[nt] = (v4f){0.f, 0.f, 0.f, 0.f};
#pragma unroll
    for (int kc = 0; kc < 8; ++kc) {
        v8s A3 = *(const v8s*)&Pl[(wv * 16 + (l & 15)) * 264 + kc * 32 + (l >> 4) * 8];
#pragma unroll
        for (int nt = 0; nt < 4; ++nt) {
            size_t off = kb + (size_t)(nt * 16 + (l & 15)) * KP_ + kc * 32 + (l >> 4) * 8;
            v8s B3 = *(const v8s*)(Vp_hi + off);
            acc3[nt] = __builtin_amdgcn_mfma_f32_16x16x32_bf16(A3, B3, acc3[nt], 0, 0, 0);
        }
    }
    float* out_b = outg + ((size_t)b * S_ + st * 64) * D_;
#pragma unroll
    for (int nt = 0; nt < 4; ++nt)
#pragma unroll
        for (int r = 0; r < 4; ++r) {
            int s_loc = wv * 16 + (l >> 4) * 4 + r;
            out_b[(size_t)s_loc * D_ + nt * 16 + (l & 15)] = acc3[nt][r];
        }
}

extern "C" void kernel_launch(void* const* d_in, const int* in_sizes, int n_in,
                              void* d_out, int out_size, void* d_ws, size_t ws_size,
                              hipStream_t stream) {
    const float* Q   = (const float*)d_in[0];
    const float* K   = (const float*)d_in[1];
    const float* V   = (const float*)d_in[2];
    const float* E_w = (const float*)d_in[3];
    const float* E_b = (const float*)d_in[4];
    const float* F_w = (const float*)d_in[5];
    const float* F_b = (const float*)d_in[6];

    float* out  = (float*)d_out;                        // [B,S,D]
    float* attn = out + (size_t)B_ * S_ * D_;           // [B,S,KP]

    // ws: bf16 planes (9.5 MB total)
    short* Whi   = (short*)d_ws;                        // [2][KP][S]  4 MB
    short* Wlo   = Whi + (size_t)2 * KP_ * S_;          // 4 MB
    short* Kp_hi = Wlo + (size_t)2 * KP_ * S_;          // [B][KP][D] k-major, 512 KB
    short* Kp_lo = Kp_hi + (size_t)B_ * KP_ * D_;
    short* Vp_hi = Kp_lo + (size_t)B_ * KP_ * D_;       // [B][D][KP] d-major

    // partials live in the attn output region (dead until attn_mfma_kernel)
    float* PpartK = attn;                               // [8][B][KP*D]  8 MB
    float* PpartV = attn + (size_t)8 * B_ * KP_ * D_;   // [8][B][KP*D]  8 MB

    wcvt_kernel<<<dim3(KP_ * S_ / 4 / 256, 2), 256, 0, stream>>>(E_w, F_w, Whi, Wlo);
    proj_mfma_kernel<<<dim3(8, 2, B_), 512, 0, stream>>>(K, V, Whi, Wlo, PpartK, PpartV);
    reduce_kernel<<<dim3(512), 256, 0, stream>>>(PpartK, PpartV, E_b, F_b, Kp_hi, Kp_lo, Vp_hi);
    attn_mfma_kernel<<<dim3(S_ / 64, B_), 256, 0, stream>>>(Q, Kp_hi, Kp_lo, Vp_hi, attn, out);
}

// Round 3
// 200.104 us; speedup vs baseline: 1.0830x; 1.0830x over previous
//
#include <hip/hip_runtime.h>

// Linformer head, MFMA bf16-split rewrite. B=16, S=4096, D=64, KP=256.
// R2 changes (attn transaction-bound theory):
//  - Kp/Vp tables stored in FRAGMENT-CONTIGUOUS order (reduce_kernel permutes)
//    -> every score/PV B-fragment load is 1KB/wave dense (8 full 128B lines
//    instead of 16 half-lines).
//  - attn output stores coalesced via small f32 LDS staging (Fst): 16 dense
//    float4 row-stores/thread replace 64 scattered dword stores.
//  - launch_bounds back to (256,3): r1 showed (256,4) cut VGPR 84->64 and
//    destroyed ILP (slower despite higher occupancy).

#define B_  16
#define S_  4096
#define D_  64
#define KP_ 256

typedef short v8s __attribute__((ext_vector_type(8)));
typedef float v4f __attribute__((ext_vector_type(4)));

__device__ __forceinline__ short f2bf(float x) {        // RNE f32 -> bf16
    union { float f; unsigned u; } v; v.f = x;
    unsigned r = v.u + 0x7FFFu + ((v.u >> 16) & 1u);
    return (short)(r >> 16);
}
__device__ __forceinline__ float bf2f(short h) {
    union { float f; unsigned u; } v; v.u = ((unsigned)(unsigned short)h) << 16;
    return v.f;
}

// ---------------------------------------------------------------------------
// Kernel 1: W fp32 -> bf16 hi/lo planes. grid (1024, 2) x 256.
// ---------------------------------------------------------------------------
__global__ __launch_bounds__(256)
void wcvt_kernel(const float* __restrict__ E_w, const float* __restrict__ F_w,
                 short* __restrict__ Whi, short* __restrict__ Wlo)
{
    const int p = blockIdx.y;
    const float* W = p ? F_w : E_w;
    const size_t i4 = (size_t)blockIdx.x * 256 + threadIdx.x;   // float4 idx
    float4 v = ((const float4*)W)[i4];
    short4 h, lo;
    h.x = f2bf(v.x); lo.x = f2bf(v.x - bf2f(h.x));
    h.y = f2bf(v.y); lo.y = f2bf(v.y - bf2f(h.y));
    h.z = f2bf(v.z); lo.z = f2bf(v.z - bf2f(h.z));
    h.w = f2bf(v.w); lo.w = f2bf(v.w - bf2f(h.w));
    const size_t o = (size_t)p * (KP_ * S_) + i4 * 4;
    *(short4*)(Whi + o) = h;
    *(short4*)(Wlo + o) = lo;
}

// ---------------------------------------------------------------------------
// Kernel 2: projections via MFMA, split-S partials. (unchanged)
// ---------------------------------------------------------------------------
__global__ __launch_bounds__(512, 2)
void proj_mfma_kernel(const float* __restrict__ Kg, const float* __restrict__ Vg,
                      const short* __restrict__ Whi, const short* __restrict__ Wlo,
                      float* __restrict__ PpartK, float* __restrict__ PpartV)
{
    const int sc = blockIdx.x;     // s-chunk of 512
    const int p  = blockIdx.y;     // 0 -> Kp, 1 -> Vp
    const int b  = blockIdx.z;

    const float* src = (p ? Vg : Kg) + ((size_t)b * S_ + sc * 512) * D_;
    const short* Wh = Whi + (size_t)p * KP_ * S_ + sc * 512;
    const short* Wl = Wlo + (size_t)p * KP_ * S_ + sc * 512;

    __shared__ __align__(16) short Af[2][2][4][512];  // [buf][plane][mt=d/16][fraglane*8] 16KB

    const int t  = threadIdx.x;
    const int wv = t >> 6;
    const int l  = t & 63;

    v4f acc[2][4];
#pragma unroll
    for (int i = 0; i < 2; ++i)
#pragma unroll
        for (int m = 0; m < 4; ++m) acc[i][m] = (v4f){0.f, 0.f, 0.f, 0.f};

    const bool do_stage = (t < 256);
    const int sd   = t & 63;
    const int soct = (t >> 6) & 3;
    const int smt  = sd >> 4;
    const int sfl  = (sd & 15) + soct * 16;

    float g[8];
    if (do_stage) {
        const float* sp = src + (size_t)(soct * 8) * D_ + sd;
#pragma unroll
        for (int j = 0; j < 8; ++j) g[j] = sp[(size_t)j * D_];
        v8s hi, lo;
#pragma unroll
        for (int j = 0; j < 8; ++j) { short h = f2bf(g[j]); hi[j] = h; lo[j] = f2bf(g[j] - bf2f(h)); }
        *(v8s*)&Af[0][0][smt][sfl * 8] = hi;
        *(v8s*)&Af[0][1][smt][sfl * 8] = lo;
    }
    __syncthreads();

    const int krow0 = wv * 32;   // wave's 32-wide k range

    for (int st = 0; st < 16; ++st) {
        const int cur = st & 1;
        if (st + 1 < 16 && do_stage) {
            const float* sp = src + (size_t)((st + 1) * 32 + soct * 8) * D_ + sd;
#pragma unroll
            for (int j = 0; j < 8; ++j) g[j] = sp[(size_t)j * D_];
        }
        v8s wh[2], wl2[2];
#pragma unroll
        for (int i = 0; i < 2; ++i) {
            size_t off = (size_t)(krow0 + i * 16 + (l & 15)) * S_ + st * 32 + (l >> 4) * 8;
            wh[i]  = *(const v8s*)(Wh + off);
            wl2[i] = *(const v8s*)(Wl + off);
        }
        v8s sh[4], sl[4];
#pragma unroll
        for (int m = 0; m < 4; ++m) {
            sh[m] = *(const v8s*)&Af[cur][0][m][l * 8];
            sl[m] = *(const v8s*)&Af[cur][1][m][l * 8];
        }
        if (p == 0) {       // C[k,d] = W @ src : A=W, B=src
#pragma unroll
            for (int i = 0; i < 2; ++i)
#pragma unroll
                for (int m = 0; m < 4; ++m) {
                    acc[i][m] = __builtin_amdgcn_mfma_f32_16x16x32_bf16(wh[i],  sh[m], acc[i][m], 0, 0, 0);
                    acc[i][m] = __builtin_amdgcn_mfma_f32_16x16x32_bf16(wh[i],  sl[m], acc[i][m], 0, 0, 0);
                    acc[i][m] = __builtin_amdgcn_mfma_f32_16x16x32_bf16(wl2[i], sh[m], acc[i][m], 0, 0, 0);
                }
        } else {            // C'[d,k] = src^T @ W^T : A=src, B=W
#pragma unroll
            for (int i = 0; i < 2; ++i)
#pragma unroll
                for (int m = 0; m < 4; ++m) {
                    acc[i][m] = __builtin_amdgcn_mfma_f32_16x16x32_bf16(sh[m], wh[i],  acc[i][m], 0, 0, 0);
                    acc[i][m] = __builtin_amdgcn_mfma_f32_16x16x32_bf16(sl[m], wh[i],  acc[i][m], 0, 0, 0);
                    acc[i][m] = __builtin_amdgcn_mfma_f32_16x16x32_bf16(sh[m], wl2[i], acc[i][m], 0, 0, 0);
                }
        }
        if (st + 1 < 16 && do_stage) {
            v8s hi, lo;
#pragma unroll
            for (int j = 0; j < 8; ++j) { short h = f2bf(g[j]); hi[j] = h; lo[j] = f2bf(g[j] - bf2f(h)); }
            *(v8s*)&Af[cur ^ 1][0][smt][sfl * 8] = hi;
            *(v8s*)&Af[cur ^ 1][1][smt][sfl * 8] = lo;
        }
        __syncthreads();
    }

    if (p == 0) {
        float* outp = PpartK + ((size_t)sc * B_ + b) * (KP_ * D_);
#pragma unroll
        for (int i = 0; i < 2; ++i)
#pragma unroll
            for (int m = 0; m < 4; ++m)
#pragma unroll
                for (int r = 0; r < 4; ++r) {
                    int k = krow0 + i * 16 + (l >> 4) * 4 + r;
                    int d = m * 16 + (l & 15);
                    outp[(size_t)k * D_ + d] = acc[i][m][r];
                }
    } else {
        float* outp = PpartV + ((size_t)sc * B_ + b) * (KP_ * D_);
#pragma unroll
        for (int i = 0; i < 2; ++i)
#pragma unroll
            for (int m = 0; m < 4; ++m)
#pragma unroll
                for (int r = 0; r < 4; ++r) {
                    int d = m * 16 + (l >> 4) * 4 + r;
                    int k = krow0 + i * 16 + (l & 15);
                    outp[(size_t)d * KP_ + k] = acc[i][m][r];
                }
    }
}

// ---------------------------------------------------------------------------
// Kernel 3: reduce partials + bias -> bf16 planes, FRAGMENT-CONTIGUOUS order.
// Kp frag layout: KpF[((b*2+kd)*16+nt)*512 + lane*8 + j]
//   = Kp[b][k=nt*16+(lane&15)][d=kd*32+(lane>>4)*8+j]
// Vp frag layout: VpF[((b*8+kc)*4+nt)*512 + lane*8 + j]
//   = Vp[b][d=nt*16+(lane&15)][k=kc*32+(lane>>4)*8+j]
// -> attn-kernel B-fragment loads become lane-contiguous 1KB/wave.
// ---------------------------------------------------------------------------
__global__ __launch_bounds__(256)
void reduce_kernel(const float* __restrict__ PpartK, const float* __restrict__ PpartV,
                   const float* __restrict__ E_b, const float* __restrict__ F_b,
                   short* __restrict__ Kp_hi, short* __restrict__ Kp_lo,
                   short* __restrict__ Vp_hi)
{
    const int j    = blockIdx.x * 256 + threadIdx.x;   // 0..131071
    const int side = j >> 16;                          // block-uniform
    const int i4   = j & 65535;
    const int flat = i4 * 4;                           // b*16384 + dk
    const int b    = flat >> 14;
    const int dk   = flat & 16383;

    if (side == 0) {
        float4 a = make_float4(0.f, 0.f, 0.f, 0.f);
#pragma unroll
        for (int sc = 0; sc < 8; ++sc) {
            float4 v = *(const float4*)(PpartK + ((size_t)sc * B_ + b) * (KP_ * D_) + dk);
            a.x += v.x; a.y += v.y; a.z += v.z; a.w += v.w;
        }
        const int k = dk >> 6, d = dk & 63;            // d % 4 == 0
        float be = E_b[k];
        a.x += be; a.y += be; a.z += be; a.w += be;
        short4 h, lo;
        h.x = f2bf(a.x); lo.x = f2bf(a.x - bf2f(h.x));
        h.y = f2bf(a.y); lo.y = f2bf(a.y - bf2f(h.y));
        h.z = f2bf(a.z); lo.z = f2bf(a.z - bf2f(h.z));
        h.w = f2bf(a.w); lo.w = f2bf(a.w - bf2f(h.w));
        // fragment-contiguous address (4 consecutive d stay contiguous: j=d&7 in {0,4})
        const size_t fo = (((size_t)b * 2 + (d >> 5)) * 16 + (k >> 4)) * 512
                        + (size_t)((k & 15) + ((d >> 3) & 3) * 16) * 8 + (d & 7);
        *(short4*)(Kp_hi + fo) = h;
        *(short4*)(Kp_lo + fo) = lo;
    } else {
        float4 a = make_float4(0.f, 0.f, 0.f, 0.f);
#pragma unroll
        for (int sc = 0; sc < 8; ++sc) {
            float4 v = *(const float4*)(PpartV + ((size_t)sc * B_ + b) * (KP_ * D_) + dk);
            a.x += v.x; a.y += v.y; a.z += v.z; a.w += v.w;
        }
        const int d = dk >> 8, k = dk & 255;           // k % 4 == 0
        float4 bf = *(const float4*)(F_b + k);
        a.x += bf.x; a.y += bf.y; a.z += bf.z; a.w += bf.w;
        short4 h;
        h.x = f2bf(a.x); h.y = f2bf(a.y); h.z = f2bf(a.z); h.w = f2bf(a.w);
        const size_t fo = (((size_t)b * 8 + (k >> 5)) * 4 + (d >> 4)) * 512
                        + (size_t)((d & 15) + ((k >> 3) & 3) * 16) * 8 + (k & 7);
        *(short4*)(Vp_hi + fo) = h;
    }
}

// ---------------------------------------------------------------------------
// Kernel 4: scores -> softmax -> attn write -> out, all MFMA.
// grid (64 st, 16 b) x 256 thr (4 waves); wave owns 16 s-rows.
// LDS: union(Qf 16KB, Pl 33KB) + Fst f32 staging 16.9KB = 50688 B -> 3 blk/CU.
// B-fragment loads now 1KB/wave dense (fragment-order tables).
// attn stores: f32 via Fst LDS round-trip -> 16 dense float4 row-stores.
// ---------------------------------------------------------------------------
__global__ __launch_bounds__(256, 3)
void attn_mfma_kernel(const float* __restrict__ Qg,
                      const short* __restrict__ Kp_hi, const short* __restrict__ Kp_lo,
                      const short* __restrict__ Vp_hi,
                      float* __restrict__ attn_out, float* __restrict__ outg)
{
    const int st = blockIdx.x;
    const int b  = blockIdx.y;
    const int t  = threadIdx.x;
    const int wv = t >> 6;
    const int l  = t & 63;

    __shared__ __align__(16) short smem[64 * 264];     // union: Qf (first 16KB) / Pl
    __shared__ __align__(16) float Fst[4][4][264];     // per-wave f32 row staging
    short (*Qf)[2][4][512] = (short (*)[2][4][512])smem;   // [kd][plane][mt][fraglane*8]
    short* Pl = smem;                                  // attn tile, pitch 264

    {   // stage Q fragments (hi/lo)
        const int s    = t & 63;
        const int doct = t >> 6;
        const float* qrow = Qg + ((size_t)b * S_ + st * 64 + s) * D_;
        const int mt = s >> 4, fl = (s & 15) + doct * 16;
#pragma unroll
        for (int kd = 0; kd < 2; ++kd) {
            float4 v0 = *(const float4*)(qrow + kd * 32 + doct * 8);
            float4 v1 = *(const float4*)(qrow + kd * 32 + doct * 8 + 4);
            float gq[8] = {v0.x, v0.y, v0.z, v0.w, v1.x, v1.y, v1.z, v1.w};
            v8s hi, lo;
#pragma unroll
            for (int jj = 0; jj < 8; ++jj) { short h = f2bf(gq[jj]); hi[jj] = h; lo[jj] = f2bf(gq[jj] - bf2f(h)); }
            *(v8s*)&Qf[kd][0][mt][fl * 8] = hi;
            *(v8s*)&Qf[kd][1][mt][fl * 8] = lo;
        }
    }
    __syncthreads();

    // scores: C2[16 s x 256 k], 3-term split; B fragments lane-contiguous
    v4f acc2[16];
#pragma unroll
    for (int nt = 0; nt < 16; ++nt) acc2[nt] = (v4f){0.f, 0.f, 0.f, 0.f};
#pragma unroll
    for (int kd = 0; kd < 2; ++kd) {
        v8s Ah = *(const v8s*)&Qf[kd][0][wv][l * 8];
        v8s Al = *(const v8s*)&Qf[kd][1][wv][l * 8];
#pragma unroll
        for (int nt = 0; nt < 16; ++nt) {
            size_t off = (((size_t)b * 2 + kd) * 16 + nt) * 512 + (size_t)l * 8;
            v8s Bh = *(const v8s*)(Kp_hi + off);
            v8s Bl = *(const v8s*)(Kp_lo + off);
            acc2[nt] = __builtin_amdgcn_mfma_f32_16x16x32_bf16(Ah, Bh, acc2[nt], 0, 0, 0);
            acc2[nt] = __builtin_amdgcn_mfma_f32_16x16x32_bf16(Al, Bh, acc2[nt], 0, 0, 0);
            acc2[nt] = __builtin_amdgcn_mfma_f32_16x16x32_bf16(Ah, Bl, acc2[nt], 0, 0, 0);
        }
    }
    __syncthreads();   // Qf dead from here; Pl may now reuse the LDS

    // softmax per row (C layout: row = wv*16 + (l>>4)*4 + r, col = nt*16 + (l&15))
    const float scale = 0.125f;   // 1/sqrt(64)
    float* attn_b = attn_out + ((size_t)b * S_ + st * 64) * KP_;
    const int g = l >> 4;
#pragma unroll
    for (int r = 0; r < 4; ++r) {
        float m = -3.4e38f;
#pragma unroll
        for (int nt = 0; nt < 16; ++nt) m = fmaxf(m, acc2[nt][r]);
        m = fmaxf(m, __shfl_xor(m, 1));
        m = fmaxf(m, __shfl_xor(m, 2));
        m = fmaxf(m, __shfl_xor(m, 4));
        m = fmaxf(m, __shfl_xor(m, 8));
        float sum = 0.f;
#pragma unroll
        for (int nt = 0; nt < 16; ++nt) {
            float e = __expf((acc2[nt][r] - m) * scale);
            acc2[nt][r] = e; sum += e;
        }
        sum += __shfl_xor(sum, 1);
        sum += __shfl_xor(sum, 2);
        sum += __shfl_xor(sum, 4);
        sum += __shfl_xor(sum, 8);
        const float inv = 1.f / sum;
        const int s_loc = wv * 16 + g * 4 + r;
#pragma unroll
        for (int nt = 0; nt < 16; ++nt) {
            float pv = acc2[nt][r] * inv;
            Fst[wv][g][nt * 16 + (l & 15)] = pv;               // f32 for coalesced store
            Pl[s_loc * 264 + nt * 16 + (l & 15)] = f2bf(pv);   // bf16 for PV
        }
        // coalesced attn store: one dense 1KB row per instr (same-wave LDS RAW,
        // in-order DS + compiler lgkmcnt — same idiom as the proven Pl->PV path)
#pragma unroll
        for (int gg = 0; gg < 4; ++gg) {
            float4 vv = *(const float4*)&Fst[wv][gg][l * 4];
            *(float4*)(attn_b + (size_t)(wv * 16 + gg * 4 + r) * KP_ + l * 4) = vv;
        }
    }
    // PV: rows wv*16..+16 written by this wave only -> no barrier needed
    v4f acc3[4];
#pragma unroll
    for (int nt = 0; nt < 4; ++nt) acc3[nt] = (v4f){0.f, 0.f, 0.f, 0.f};
#pragma unroll
    for (int kc = 0; kc < 8; ++kc) {
        v8s A3 = *(const v8s*)&Pl[(wv * 16 + (l & 15)) * 264 + kc * 32 + (l >> 4) * 8];
#pragma unroll
        for (int nt = 0; nt < 4; ++nt) {
            size_t off = (((size_t)b * 8 + kc) * 4 + nt) * 512 + (size_t)l * 8;
            v8s B3 = *(const v8s*)(Vp_hi + off);
            acc3[nt] = __builtin_amdgcn_mfma_f32_16x16x32_bf16(A3, B3, acc3[nt], 0, 0, 0);
        }
    }
    float* out_b = outg + ((size_t)b * S_ + st * 64) * D_;
#pragma unroll
    for (int nt = 0; nt < 4; ++nt)
#pragma unroll
        for (int r = 0; r < 4; ++r) {
            int s_loc = wv * 16 + (l >> 4) * 4 + r;
            out_b[(size_t)s_loc * D_ + nt * 16 + (l & 15)] = acc3[nt][r];
        }
}

extern "C" void kernel_launch(void* const* d_in, const int* in_sizes, int n_in,
                              void* d_out, int out_size, void* d_ws, size_t ws_size,
                              hipStream_t stream) {
    const float* Q   = (const float*)d_in[0];
    const float* K   = (const float*)d_in[1];
    const float* V   = (const float*)d_in[2];
    const float* E_w = (const float*)d_in[3];
    const float* E_b = (const float*)d_in[4];
    const float* F_w = (const float*)d_in[5];
    const float* F_b = (const float*)d_in[6];

    float* out  = (float*)d_out;                        // [B,S,D]
    float* attn = out + (size_t)B_ * S_ * D_;           // [B,S,KP]

    // ws: bf16 planes (9.5 MB total)
    short* Whi   = (short*)d_ws;                        // [2][KP][S]  4 MB
    short* Wlo   = Whi + (size_t)2 * KP_ * S_;          // 4 MB
    short* Kp_hi = Wlo + (size_t)2 * KP_ * S_;          // frag-order, 512 KB
    short* Kp_lo = Kp_hi + (size_t)B_ * KP_ * D_;
    short* Vp_hi = Kp_lo + (size_t)B_ * KP_ * D_;       // frag-order

    // partials live in the attn output region (dead until attn_mfma_kernel)
    float* PpartK = attn;                               // [8][B][KP*D]  8 MB
    float* PpartV = attn + (size_t)8 * B_ * KP_ * D_;   // [8][B][KP*D]  8 MB

    wcvt_kernel<<<dim3(KP_ * S_ / 4 / 256, 2), 256, 0, stream>>>(E_w, F_w, Whi, Wlo);
    proj_mfma_kernel<<<dim3(8, 2, B_), 512, 0, stream>>>(K, V, Whi, Wlo, PpartK, PpartV);
    reduce_kernel<<<dim3(512), 256, 0, stream>>>(PpartK, PpartV, E_b, F_b, Kp_hi, Kp_lo, Vp_hi);
    attn_mfma_kernel<<<dim3(S_ / 64, B_), 256, 0, stream>>>(Q, Kp_hi, Kp_lo, Vp_hi, attn, out);
}

// Round 4
// 183.806 us; speedup vs baseline: 1.1790x; 1.0887x over previous
//
#include <hip/hip_runtime.h>

// Linformer head, MFMA bf16-split rewrite. B=16, S=4096, D=64, KP=256.
// R3: frag-contiguous Kp/Vp tables + Fst-staged coalesced attn stores (54.6us attn).
// R4: attn score/PV B-operands are block-shared -> stage them in LDS once per
//     block instead of 4x redundant per-wave L2 loads (~256KB -> 64KB L2/block
//     for scores). Kp_hi[kd] -> Fst region (dead during scores), Kp_lo[kd] ->
//     smem+16KB (Pl rows 31+, dead during scores). Vp kc0-3 -> Fst region
//     (dead after attn stores). MFMA B-frags now ds_read_b128 (12cyc) not L2
//     (~300cyc). Occupancy is VGPR-locked at 3 waves/SIMD (148 total regs);
//     R1 proved forcing 4 costs more ILP than it gains -> attack latency, not
//     occupancy.

#define B_  16
#define S_  4096
#define D_  64
#define KP_ 256

typedef short v8s __attribute__((ext_vector_type(8)));
typedef float v4f __attribute__((ext_vector_type(4)));

__device__ __forceinline__ short f2bf(float x) {        // RNE f32 -> bf16
    union { float f; unsigned u; } v; v.f = x;
    unsigned r = v.u + 0x7FFFu + ((v.u >> 16) & 1u);
    return (short)(r >> 16);
}
__device__ __forceinline__ float bf2f(short h) {
    union { float f; unsigned u; } v; v.u = ((unsigned)(unsigned short)h) << 16;
    return v.f;
}

// ---------------------------------------------------------------------------
// Kernel 1: W fp32 -> bf16 hi/lo planes. grid (1024, 2) x 256.
// ---------------------------------------------------------------------------
__global__ __launch_bounds__(256)
void wcvt_kernel(const float* __restrict__ E_w, const float* __restrict__ F_w,
                 short* __restrict__ Whi, short* __restrict__ Wlo)
{
    const int p = blockIdx.y;
    const float* W = p ? F_w : E_w;
    const size_t i4 = (size_t)blockIdx.x * 256 + threadIdx.x;   // float4 idx
    float4 v = ((const float4*)W)[i4];
    short4 h, lo;
    h.x = f2bf(v.x); lo.x = f2bf(v.x - bf2f(h.x));
    h.y = f2bf(v.y); lo.y = f2bf(v.y - bf2f(h.y));
    h.z = f2bf(v.z); lo.z = f2bf(v.z - bf2f(h.z));
    h.w = f2bf(v.w); lo.w = f2bf(v.w - bf2f(h.w));
    const size_t o = (size_t)p * (KP_ * S_) + i4 * 4;
    *(short4*)(Whi + o) = h;
    *(short4*)(Wlo + o) = lo;
}

// ---------------------------------------------------------------------------
// Kernel 2: projections via MFMA, split-S partials. (unchanged)
// ---------------------------------------------------------------------------
__global__ __launch_bounds__(512, 2)
void proj_mfma_kernel(const float* __restrict__ Kg, const float* __restrict__ Vg,
                      const short* __restrict__ Whi, const short* __restrict__ Wlo,
                      float* __restrict__ PpartK, float* __restrict__ PpartV)
{
    const int sc = blockIdx.x;     // s-chunk of 512
    const int p  = blockIdx.y;     // 0 -> Kp, 1 -> Vp
    const int b  = blockIdx.z;

    const float* src = (p ? Vg : Kg) + ((size_t)b * S_ + sc * 512) * D_;
    const short* Wh = Whi + (size_t)p * KP_ * S_ + sc * 512;
    const short* Wl = Wlo + (size_t)p * KP_ * S_ + sc * 512;

    __shared__ __align__(16) short Af[2][2][4][512];  // [buf][plane][mt=d/16][fraglane*8] 16KB

    const int t  = threadIdx.x;
    const int wv = t >> 6;
    const int l  = t & 63;

    v4f acc[2][4];
#pragma unroll
    for (int i = 0; i < 2; ++i)
#pragma unroll
        for (int m = 0; m < 4; ++m) acc[i][m] = (v4f){0.f, 0.f, 0.f, 0.f};

    const bool do_stage = (t < 256);
    const int sd   = t & 63;
    const int soct = (t >> 6) & 3;
    const int smt  = sd >> 4;
    const int sfl  = (sd & 15) + soct * 16;

    float g[8];
    if (do_stage) {
        const float* sp = src + (size_t)(soct * 8) * D_ + sd;
#pragma unroll
        for (int j = 0; j < 8; ++j) g[j] = sp[(size_t)j * D_];
        v8s hi, lo;
#pragma unroll
        for (int j = 0; j < 8; ++j) { short h = f2bf(g[j]); hi[j] = h; lo[j] = f2bf(g[j] - bf2f(h)); }
        *(v8s*)&Af[0][0][smt][sfl * 8] = hi;
        *(v8s*)&Af[0][1][smt][sfl * 8] = lo;
    }
    __syncthreads();

    const int krow0 = wv * 32;   // wave's 32-wide k range

    for (int st = 0; st < 16; ++st) {
        const int cur = st & 1;
        if (st + 1 < 16 && do_stage) {
            const float* sp = src + (size_t)((st + 1) * 32 + soct * 8) * D_ + sd;
#pragma unroll
            for (int j = 0; j < 8; ++j) g[j] = sp[(size_t)j * D_];
        }
        v8s wh[2], wl2[2];
#pragma unroll
        for (int i = 0; i < 2; ++i) {
            size_t off = (size_t)(krow0 + i * 16 + (l & 15)) * S_ + st * 32 + (l >> 4) * 8;
            wh[i]  = *(const v8s*)(Wh + off);
            wl2[i] = *(const v8s*)(Wl + off);
        }
        v8s sh[4], sl[4];
#pragma unroll
        for (int m = 0; m < 4; ++m) {
            sh[m] = *(const v8s*)&Af[cur][0][m][l * 8];
            sl[m] = *(const v8s*)&Af[cur][1][m][l * 8];
        }
        if (p == 0) {       // C[k,d] = W @ src : A=W, B=src
#pragma unroll
            for (int i = 0; i < 2; ++i)
#pragma unroll
                for (int m = 0; m < 4; ++m) {
                    acc[i][m] = __builtin_amdgcn_mfma_f32_16x16x32_bf16(wh[i],  sh[m], acc[i][m], 0, 0, 0);
                    acc[i][m] = __builtin_amdgcn_mfma_f32_16x16x32_bf16(wh[i],  sl[m], acc[i][m], 0, 0, 0);
                    acc[i][m] = __builtin_amdgcn_mfma_f32_16x16x32_bf16(wl2[i], sh[m], acc[i][m], 0, 0, 0);
                }
        } else {            // C'[d,k] = src^T @ W^T : A=src, B=W
#pragma unroll
            for (int i = 0; i < 2; ++i)
#pragma unroll
                for (int m = 0; m < 4; ++m) {
                    acc[i][m] = __builtin_amdgcn_mfma_f32_16x16x32_bf16(sh[m], wh[i],  acc[i][m], 0, 0, 0);
                    acc[i][m] = __builtin_amdgcn_mfma_f32_16x16x32_bf16(sl[m], wh[i],  acc[i][m], 0, 0, 0);
                    acc[i][m] = __builtin_amdgcn_mfma_f32_16x16x32_bf16(sh[m], wl2[i], acc[i][m], 0, 0, 0);
                }
        }
        if (st + 1 < 16 && do_stage) {
            v8s hi, lo;
#pragma unroll
            for (int j = 0; j < 8; ++j) { short h = f2bf(g[j]); hi[j] = h; lo[j] = f2bf(g[j] - bf2f(h)); }
            *(v8s*)&Af[cur ^ 1][0][smt][sfl * 8] = hi;
            *(v8s*)&Af[cur ^ 1][1][smt][sfl * 8] = lo;
        }
        __syncthreads();
    }

    if (p == 0) {
        float* outp = PpartK + ((size_t)sc * B_ + b) * (KP_ * D_);
#pragma unroll
        for (int i = 0; i < 2; ++i)
#pragma unroll
            for (int m = 0; m < 4; ++m)
#pragma unroll
                for (int r = 0; r < 4; ++r) {
                    int k = krow0 + i * 16 + (l >> 4) * 4 + r;
                    int d = m * 16 + (l & 15);
                    outp[(size_t)k * D_ + d] = acc[i][m][r];
                }
    } else {
        float* outp = PpartV + ((size_t)sc * B_ + b) * (KP_ * D_);
#pragma unroll
        for (int i = 0; i < 2; ++i)
#pragma unroll
            for (int m = 0; m < 4; ++m)
#pragma unroll
                for (int r = 0; r < 4; ++r) {
                    int d = m * 16 + (l >> 4) * 4 + r;
                    int k = krow0 + i * 16 + (l & 15);
                    outp[(size_t)d * KP_ + k] = acc[i][m][r];
                }
    }
}

// ---------------------------------------------------------------------------
// Kernel 3: reduce partials + bias -> bf16 planes, FRAGMENT-CONTIGUOUS order.
// (unchanged from R3)
// ---------------------------------------------------------------------------
__global__ __launch_bounds__(256)
void reduce_kernel(const float* __restrict__ PpartK, const float* __restrict__ PpartV,
                   const float* __restrict__ E_b, const float* __restrict__ F_b,
                   short* __restrict__ Kp_hi, short* __restrict__ Kp_lo,
                   short* __restrict__ Vp_hi)
{
    const int j    = blockIdx.x * 256 + threadIdx.x;   // 0..131071
    const int side = j >> 16;                          // block-uniform
    const int i4   = j & 65535;
    const int flat = i4 * 4;                           // b*16384 + dk
    const int b    = flat >> 14;
    const int dk   = flat & 16383;

    if (side == 0) {
        float4 a = make_float4(0.f, 0.f, 0.f, 0.f);
#pragma unroll
        for (int sc = 0; sc < 8; ++sc) {
            float4 v = *(const float4*)(PpartK + ((size_t)sc * B_ + b) * (KP_ * D_) + dk);
            a.x += v.x; a.y += v.y; a.z += v.z; a.w += v.w;
        }
        const int k = dk >> 6, d = dk & 63;            // d % 4 == 0
        float be = E_b[k];
        a.x += be; a.y += be; a.z += be; a.w += be;
        short4 h, lo;
        h.x = f2bf(a.x); lo.x = f2bf(a.x - bf2f(h.x));
        h.y = f2bf(a.y); lo.y = f2bf(a.y - bf2f(h.y));
        h.z = f2bf(a.z); lo.z = f2bf(a.z - bf2f(h.z));
        h.w = f2bf(a.w); lo.w = f2bf(a.w - bf2f(h.w));
        const size_t fo = (((size_t)b * 2 + (d >> 5)) * 16 + (k >> 4)) * 512
                        + (size_t)((k & 15) + ((d >> 3) & 3) * 16) * 8 + (d & 7);
        *(short4*)(Kp_hi + fo) = h;
        *(short4*)(Kp_lo + fo) = lo;
    } else {
        float4 a = make_float4(0.f, 0.f, 0.f, 0.f);
#pragma unroll
        for (int sc = 0; sc < 8; ++sc) {
            float4 v = *(const float4*)(PpartV + ((size_t)sc * B_ + b) * (KP_ * D_) + dk);
            a.x += v.x; a.y += v.y; a.z += v.z; a.w += v.w;
        }
        const int d = dk >> 8, k = dk & 255;           // k % 4 == 0
        float4 bf = *(const float4*)(F_b + k);
        a.x += bf.x; a.y += bf.y; a.z += bf.z; a.w += bf.w;
        short4 h;
        h.x = f2bf(a.x); h.y = f2bf(a.y); h.z = f2bf(a.z); h.w = f2bf(a.w);
        const size_t fo = (((size_t)b * 8 + (k >> 5)) * 4 + (d >> 4)) * 512
                        + (size_t)((d & 15) + ((k >> 3) & 3) * 16) * 8 + (k & 7);
        *(short4*)(Vp_hi + fo) = h;
    }
}

// ---------------------------------------------------------------------------
// Kernel 4: scores -> softmax -> attn write -> out, all MFMA.
// grid (64 st, 16 b) x 256 thr (4 waves); wave owns 16 s-rows.
// LDS 50688 B (3 blk/CU, VGPR-locked anyway). Regions time-shared:
//   smem[0..8192 shorts)  : Qf (live: stage..score end), then Pl rows 0..30
//   smem[8192..16384)     : KLl staging (score), then Pl rows 31..63
//   Fst 16.9KB            : KLh staging (score), f32 store staging (softmax),
//                           Vp kc0-3 staging (PV)
// ---------------------------------------------------------------------------
__global__ __launch_bounds__(256, 3)
void attn_mfma_kernel(const float* __restrict__ Qg,
                      const short* __restrict__ Kp_hi, const short* __restrict__ Kp_lo,
                      const short* __restrict__ Vp_hi,
                      float* __restrict__ attn_out, float* __restrict__ outg)
{
    const int st = blockIdx.x;
    const int b  = blockIdx.y;
    const int t  = threadIdx.x;
    const int wv = t >> 6;
    const int l  = t & 63;

    __shared__ __align__(16) short smem[64 * 264];     // union: Qf+KLl / Pl
    __shared__ __align__(16) float Fst[4][4][264];     // union: KLh / store staging / VL
    short (*Qf)[2][4][512] = (short (*)[2][4][512])smem;   // [kd][plane][mt][fraglane*8]
    short* Pl  = smem;                                 // attn tile, pitch 264
    short* KLl = smem + 8192;                          // 16KB lo-plane staging
    short* KLh = (short*)&Fst[0][0][0];                // 16KB hi-plane staging

    {   // stage Q fragments (hi/lo)
        const int s    = t & 63;
        const int doct = t >> 6;
        const float* qrow = Qg + ((size_t)b * S_ + st * 64 + s) * D_;
        const int mt = s >> 4, fl = (s & 15) + doct * 16;
#pragma unroll
        for (int kd = 0; kd < 2; ++kd) {
            float4 v0 = *(const float4*)(qrow + kd * 32 + doct * 8);
            float4 v1 = *(const float4*)(qrow + kd * 32 + doct * 8 + 4);
            float gq[8] = {v0.x, v0.y, v0.z, v0.w, v1.x, v1.y, v1.z, v1.w};
            v8s hi, lo;
#pragma unroll
            for (int jj = 0; jj < 8; ++jj) { short h = f2bf(gq[jj]); hi[jj] = h; lo[jj] = f2bf(gq[jj] - bf2f(h)); }
            *(v8s*)&Qf[kd][0][mt][fl * 8] = hi;
            *(v8s*)&Qf[kd][1][mt][fl * 8] = lo;
        }
    }
    __syncthreads();

    // scores: C2[16 s x 256 k], 3-term split; B-operands LDS-staged per kd
    // (block-shared: stage once instead of 4 waves x same 32KB from L2)
    v4f acc2[16];
#pragma unroll
    for (int nt = 0; nt < 16; ++nt) acc2[nt] = (v4f){0.f, 0.f, 0.f, 0.f};
#pragma unroll
    for (int kd = 0; kd < 2; ++kd) {
        {   // cooperative copy: Kp_hi[kd] -> KLh, Kp_lo[kd] -> KLl (16KB each)
            const size_t tbl = (((size_t)b * 2 + kd) * 16) * 512;   // shorts
            const int4* gh = (const int4*)(Kp_hi + tbl);
            const int4* gl = (const int4*)(Kp_lo + tbl);
            int4* lh = (int4*)KLh;
            int4* ll = (int4*)KLl;
#pragma unroll
            for (int i = 0; i < 4; ++i) lh[t + i * 256] = gh[t + i * 256];
#pragma unroll
            for (int i = 0; i < 4; ++i) ll[t + i * 256] = gl[t + i * 256];
        }
        __syncthreads();
        v8s Ah = *(const v8s*)&Qf[kd][0][wv][l * 8];
        v8s Al = *(const v8s*)&Qf[kd][1][wv][l * 8];
#pragma unroll
        for (int nt = 0; nt < 16; ++nt) {
            v8s Bh = *(const v8s*)&KLh[nt * 512 + l * 8];
            v8s Bl = *(const v8s*)&KLl[nt * 512 + l * 8];
            acc2[nt] = __builtin_amdgcn_mfma_f32_16x16x32_bf16(Ah, Bh, acc2[nt], 0, 0, 0);
            acc2[nt] = __builtin_amdgcn_mfma_f32_16x16x32_bf16(Al, Bh, acc2[nt], 0, 0, 0);
            acc2[nt] = __builtin_amdgcn_mfma_f32_16x16x32_bf16(Ah, Bl, acc2[nt], 0, 0, 0);
        }
        __syncthreads();   // staging buffers reusable (next kd / Pl / Fst)
    }

    // softmax per row (C layout: row = wv*16 + (l>>4)*4 + r, col = nt*16 + (l&15))
    const float scale = 0.125f;   // 1/sqrt(64)
    float* attn_b = attn_out + ((size_t)b * S_ + st * 64) * KP_;
    const int g = l >> 4;
#pragma unroll
    for (int r = 0; r < 4; ++r) {
        float m = -3.4e38f;
#pragma unroll
        for (int nt = 0; nt < 16; ++nt) m = fmaxf(m, acc2[nt][r]);
        m = fmaxf(m, __shfl_xor(m, 1));
        m = fmaxf(m, __shfl_xor(m, 2));
        m = fmaxf(m, __shfl_xor(m, 4));
        m = fmaxf(m, __shfl_xor(m, 8));
        float sum = 0.f;
#pragma unroll
        for (int nt = 0; nt < 16; ++nt) {
            float e = __expf((acc2[nt][r] - m) * scale);
            acc2[nt][r] = e; sum += e;
        }
        sum += __shfl_xor(sum, 1);
        sum += __shfl_xor(sum, 2);
        sum += __shfl_xor(sum, 4);
        sum += __shfl_xor(sum, 8);
        const float inv = 1.f / sum;
        const int s_loc = wv * 16 + g * 4 + r;
#pragma unroll
        for (int nt = 0; nt < 16; ++nt) {
            float pv = acc2[nt][r] * inv;
            Fst[wv][g][nt * 16 + (l & 15)] = pv;               // f32 for coalesced store
            Pl[s_loc * 264 + nt * 16 + (l & 15)] = f2bf(pv);   // bf16 for PV
        }
        // coalesced attn store: one dense 1KB row per instr (same-wave LDS RAW)
#pragma unroll
        for (int gg = 0; gg < 4; ++gg) {
            float4 vv = *(const float4*)&Fst[wv][gg][l * 4];
            *(float4*)(attn_b + (size_t)(wv * 16 + gg * 4 + r) * KP_ + l * 4) = vv;
        }
    }
    // stage Vp kc0-3 (16KB) into Fst region (dead after attn stores)
    __syncthreads();
    {
        const int4* gv = (const int4*)(Vp_hi + (size_t)b * 16384);
        int4* lv = (int4*)KLh;
#pragma unroll
        for (int i = 0; i < 4; ++i) lv[t + i * 256] = gv[t + i * 256];
    }
    __syncthreads();
    // PV: rows wv*16..+16 of Pl written by this wave only
    v4f acc3[4];
#pragma unroll
    for (int nt = 0; nt < 4; ++nt) acc3[nt] = (v4f){0.f, 0.f, 0.f, 0.f};
#pragma unroll
    for (int kc = 0; kc < 8; ++kc) {
        v8s A3 = *(const v8s*)&Pl[(wv * 16 + (l & 15)) * 264 + kc * 32 + (l >> 4) * 8];
#pragma unroll
        for (int nt = 0; nt < 4; ++nt) {
            v8s B3 = (kc < 4)
                ? *(const v8s*)&KLh[(kc * 4 + nt) * 512 + l * 8]
                : *(const v8s*)(Vp_hi + (((size_t)b * 8 + kc) * 4 + nt) * 512 + (size_t)l * 8);
            acc3[nt] = __builtin_amdgcn_mfma_f32_16x16x32_bf16(A3, B3, acc3[nt], 0, 0, 0);
        }
    }
    float* out_b = outg + ((size_t)b * S_ + st * 64) * D_;
#pragma unroll
    for (int nt = 0; nt < 4; ++nt)
#pragma unroll
        for (int r = 0; r < 4; ++r) {
            int s_loc = wv * 16 + (l >> 4) * 4 + r;
            out_b[(size_t)s_loc * D_ + nt * 16 + (l & 15)] = acc3[nt][r];
        }
}

extern "C" void kernel_launch(void* const* d_in, const int* in_sizes, int n_in,
                              void* d_out, int out_size, void* d_ws, size_t ws_size,
                              hipStream_t stream) {
    const float* Q   = (const float*)d_in[0];
    const float* K   = (const float*)d_in[1];
    const float* V   = (const float*)d_in[2];
    const float* E_w = (const float*)d_in[3];
    const float* E_b = (const float*)d_in[4];
    const float* F_w = (const float*)d_in[5];
    const float* F_b = (const float*)d_in[6];

    float* out  = (float*)d_out;                        // [B,S,D]
    float* attn = out + (size_t)B_ * S_ * D_;           // [B,S,KP]

    // ws: bf16 planes (9.5 MB total)
    short* Whi   = (short*)d_ws;                        // [2][KP][S]  4 MB
    short* Wlo   = Whi + (size_t)2 * KP_ * S_;          // 4 MB
    short* Kp_hi = Wlo + (size_t)2 * KP_ * S_;          // frag-order, 512 KB
    short* Kp_lo = Kp_hi + (size_t)B_ * KP_ * D_;
    short* Vp_hi = Kp_lo + (size_t)B_ * KP_ * D_;       // frag-order

    // partials live in the attn output region (dead until attn_mfma_kernel)
    float* PpartK = attn;                               // [8][B][KP*D]  8 MB
    float* PpartV = attn + (size_t)8 * B_ * KP_ * D_;   // [8][B][KP*D]  8 MB

    wcvt_kernel<<<dim3(KP_ * S_ / 4 / 256, 2), 256, 0, stream>>>(E_w, F_w, Whi, Wlo);
    proj_mfma_kernel<<<dim3(8, 2, B_), 512, 0, stream>>>(K, V, Whi, Wlo, PpartK, PpartV);
    reduce_kernel<<<dim3(512), 256, 0, stream>>>(PpartK, PpartV, E_b, F_b, Kp_hi, Kp_lo, Vp_hi);
    attn_mfma_kernel<<<dim3(S_ / 64, B_), 256, 0, stream>>>(Q, Kp_hi, Kp_lo, Vp_hi, attn, out);
}

// Round 5
// 179.423 us; speedup vs baseline: 1.2078x; 1.0244x over previous
//
#include <hip/hip_runtime.h>

// Linformer head, MFMA bf16-split rewrite. B=16, S=4096, D=64, KP=256.
// R3: frag-contiguous Kp/Vp tables + coalesced attn stores (attn 54.6us).
// R4: attn score/PV B-operands LDS-staged once per block (attn ~40us).
// R5: apply the same transaction fix to proj:
//  - wcvt writes W planes in FRAG-TILE order (16k x 32s tiles, 512 shorts):
//    proj W loads become lane*8-dense (1KB/wave, 1 segment) instead of 16
//    disjoint 64B segments at 8KB stride.
//  - proj double-buffers W fragments in registers (prefetch next st during
//    current MFMA; manual 2x unroll for static reg indexing).
//  - attn PV: restage Vp kc4-7 into the same 16KB LDS buffer (2 barriers)
//    -> no per-wave redundant L2 reads left in PV.

#define B_  16
#define S_  4096
#define D_  64
#define KP_ 256

typedef short v8s __attribute__((ext_vector_type(8)));
typedef float v4f __attribute__((ext_vector_type(4)));

__device__ __forceinline__ short f2bf(float x) {        // RNE f32 -> bf16
    union { float f; unsigned u; } v; v.f = x;
    unsigned r = v.u + 0x7FFFu + ((v.u >> 16) & 1u);
    return (short)(r >> 16);
}
__device__ __forceinline__ float bf2f(short h) {
    union { float f; unsigned u; } v; v.u = ((unsigned)(unsigned short)h) << 16;
    return v.f;
}

// ---------------------------------------------------------------------------
// Kernel 1: W fp32 -> bf16 hi/lo planes in FRAG-TILE order. grid (1024,2)x256.
// Tile (p, k16=k>>4, sb=s>>5) of 512 shorts; within tile:
//   lane = (k&15) + ((s>>3)&3)*16, elem = s&7  ->  off = tile*512 + lane*8 + elem
// Matches proj wave load: off = ((p*16 + k16 + i)*128 + sc*16 + st)*512 + l*8.
// ---------------------------------------------------------------------------
__global__ __launch_bounds__(256)
void wcvt_kernel(const float* __restrict__ E_w, const float* __restrict__ F_w,
                 short* __restrict__ Whi, short* __restrict__ Wlo)
{
    const int p = blockIdx.y;
    const float* W = p ? F_w : E_w;
    const size_t i4 = (size_t)blockIdx.x * 256 + threadIdx.x;   // float4 idx
    float4 v = ((const float4*)W)[i4];
    short4 h, lo;
    h.x = f2bf(v.x); lo.x = f2bf(v.x - bf2f(h.x));
    h.y = f2bf(v.y); lo.y = f2bf(v.y - bf2f(h.y));
    h.z = f2bf(v.z); lo.z = f2bf(v.z - bf2f(h.z));
    h.w = f2bf(v.w); lo.w = f2bf(v.w - bf2f(h.w));
    const int k  = (int)(i4 >> 10);            // S/4 = 1024 float4 per k-row
    const int s0 = (int)(i4 & 1023) << 2;      // s0 % 4 == 0 -> same 8-block
    const size_t fo = (((size_t)p * 16 + (k >> 4)) * 128 + (s0 >> 5)) * 512
                    + (size_t)(((k & 15) + ((s0 >> 3) & 3) * 16) * 8) + (s0 & 7);
    *(short4*)(Whi + fo) = h;
    *(short4*)(Wlo + fo) = lo;
}

// ---------------------------------------------------------------------------
// Kernel 2: projections via MFMA, split-S partials.
// grid (sc 8, p 2, b 16) x 512 thr (8 waves). W loads now frag-tile dense +
// register double-buffered (prefetch next st). Partial store layout unchanged.
// ---------------------------------------------------------------------------
__global__ __launch_bounds__(512, 2)
void proj_mfma_kernel(const float* __restrict__ Kg, const float* __restrict__ Vg,
                      const short* __restrict__ Whi, const short* __restrict__ Wlo,
                      float* __restrict__ PpartK, float* __restrict__ PpartV)
{
    const int sc = blockIdx.x;     // s-chunk of 512
    const int p  = blockIdx.y;     // 0 -> Kp, 1 -> Vp
    const int b  = blockIdx.z;

    const float* src = (p ? Vg : Kg) + ((size_t)b * S_ + sc * 512) * D_;

    __shared__ __align__(16) short Af[2][2][4][512];  // [buf][plane][mt=d/16][fraglane*8] 16KB

    const int t  = threadIdx.x;
    const int wv = t >> 6;
    const int l  = t & 63;
    const int k16 = wv * 2;        // wave's base k16 tile

    // W frag-tile offset for (i, st): dense per-wave 1KB
    const size_t wbase = ((size_t)p * 16 + k16) * 128 * 512 + (size_t)(sc * 16) * 512 + (size_t)l * 8;
    // off(i, st) = wbase + i*128*512 + st*512

    v4f acc[2][4];
#pragma unroll
    for (int i = 0; i < 2; ++i)
#pragma unroll
        for (int m = 0; m < 4; ++m) acc[i][m] = (v4f){0.f, 0.f, 0.f, 0.f};

    const bool do_stage = (t < 256);
    const int sd   = t & 63;
    const int soct = (t >> 6) & 3;
    const int smt  = sd >> 4;
    const int sfl  = (sd & 15) + soct * 16;

    // issue first W loads early (independent of LDS)
    v8s whA[2], wlA[2], whB[2], wlB[2];
#pragma unroll
    for (int i = 0; i < 2; ++i) {
        size_t o = wbase + (size_t)i * 65536;
        whA[i] = *(const v8s*)(Whi + o);
        wlA[i] = *(const v8s*)(Wlo + o);
    }

    float g[8];
    if (do_stage) {
        const float* sp = src + (size_t)(soct * 8) * D_ + sd;
#pragma unroll
        for (int j = 0; j < 8; ++j) g[j] = sp[(size_t)j * D_];
        v8s hi, lo;
#pragma unroll
        for (int j = 0; j < 8; ++j) { short h = f2bf(g[j]); hi[j] = h; lo[j] = f2bf(g[j] - bf2f(h)); }
        *(v8s*)&Af[0][0][smt][sfl * 8] = hi;
        *(v8s*)&Af[0][1][smt][sfl * 8] = lo;
    }
    __syncthreads();

    auto step = [&](int st, v8s (&whc)[2], v8s (&wlc)[2], v8s (&whn)[2], v8s (&wln)[2]) {
        const int cur = st & 1;
        if (st + 1 < 16) {
            // prefetch next-st W fragments (dense 1KB/wave each)
#pragma unroll
            for (int i = 0; i < 2; ++i) {
                size_t o = wbase + (size_t)i * 65536 + (size_t)(st + 1) * 512;
                whn[i] = *(const v8s*)(Whi + o);
                wln[i] = *(const v8s*)(Wlo + o);
            }
            if (do_stage) {      // prefetch next-st src
                const float* sp = src + (size_t)((st + 1) * 32 + soct * 8) * D_ + sd;
#pragma unroll
                for (int j = 0; j < 8; ++j) g[j] = sp[(size_t)j * D_];
            }
        }
        // src fragments (LDS, fragment order: lane reads its own 16B)
        v8s sh[4], sl[4];
#pragma unroll
        for (int m = 0; m < 4; ++m) {
            sh[m] = *(const v8s*)&Af[cur][0][m][l * 8];
            sl[m] = *(const v8s*)&Af[cur][1][m][l * 8];
        }
        if (p == 0) {       // C[k,d] = W @ src : A=W, B=src
#pragma unroll
            for (int i = 0; i < 2; ++i)
#pragma unroll
                for (int m = 0; m < 4; ++m) {
                    acc[i][m] = __builtin_amdgcn_mfma_f32_16x16x32_bf16(whc[i], sh[m], acc[i][m], 0, 0, 0);
                    acc[i][m] = __builtin_amdgcn_mfma_f32_16x16x32_bf16(whc[i], sl[m], acc[i][m], 0, 0, 0);
                    acc[i][m] = __builtin_amdgcn_mfma_f32_16x16x32_bf16(wlc[i], sh[m], acc[i][m], 0, 0, 0);
                }
        } else {            // C'[d,k] = src^T @ W^T : A=src, B=W
#pragma unroll
            for (int i = 0; i < 2; ++i)
#pragma unroll
                for (int m = 0; m < 4; ++m) {
                    acc[i][m] = __builtin_amdgcn_mfma_f32_16x16x32_bf16(sh[m], whc[i], acc[i][m], 0, 0, 0);
                    acc[i][m] = __builtin_amdgcn_mfma_f32_16x16x32_bf16(sl[m], whc[i], acc[i][m], 0, 0, 0);
                    acc[i][m] = __builtin_amdgcn_mfma_f32_16x16x32_bf16(sh[m], wlc[i], acc[i][m], 0, 0, 0);
                }
        }
        if (st + 1 < 16 && do_stage) {      // convert + write next buffer
            v8s hi, lo;
#pragma unroll
            for (int j = 0; j < 8; ++j) { short h = f2bf(g[j]); hi[j] = h; lo[j] = f2bf(g[j] - bf2f(h)); }
            *(v8s*)&Af[cur ^ 1][0][smt][sfl * 8] = hi;
            *(v8s*)&Af[cur ^ 1][1][smt][sfl * 8] = lo;
        }
        __syncthreads();
    };

    for (int st2 = 0; st2 < 16; st2 += 2) {
        step(st2,     whA, wlA, whB, wlB);
        step(st2 + 1, whB, wlB, whA, wlA);
    }

    const int krow0 = wv * 32;
    if (p == 0) {
        float* outp = PpartK + ((size_t)sc * B_ + b) * (KP_ * D_);
#pragma unroll
        for (int i = 0; i < 2; ++i)
#pragma unroll
            for (int m = 0; m < 4; ++m)
#pragma unroll
                for (int r = 0; r < 4; ++r) {
                    int k = krow0 + i * 16 + (l >> 4) * 4 + r;
                    int d = m * 16 + (l & 15);
                    outp[(size_t)k * D_ + d] = acc[i][m][r];
                }
    } else {
        float* outp = PpartV + ((size_t)sc * B_ + b) * (KP_ * D_);
#pragma unroll
        for (int i = 0; i < 2; ++i)
#pragma unroll
            for (int m = 0; m < 4; ++m)
#pragma unroll
                for (int r = 0; r < 4; ++r) {
                    int d = m * 16 + (l >> 4) * 4 + r;
                    int k = krow0 + i * 16 + (l & 15);
                    outp[(size_t)d * KP_ + k] = acc[i][m][r];
                }
    }
}

// ---------------------------------------------------------------------------
// Kernel 3: reduce partials + bias -> bf16 planes, FRAGMENT-CONTIGUOUS order.
// (unchanged from R3)
// ---------------------------------------------------------------------------
__global__ __launch_bounds__(256)
void reduce_kernel(const float* __restrict__ PpartK, const float* __restrict__ PpartV,
                   const float* __restrict__ E_b, const float* __restrict__ F_b,
                   short* __restrict__ Kp_hi, short* __restrict__ Kp_lo,
                   short* __restrict__ Vp_hi)
{
    const int j    = blockIdx.x * 256 + threadIdx.x;   // 0..131071
    const int side = j >> 16;                          // block-uniform
    const int i4   = j & 65535;
    const int flat = i4 * 4;                           // b*16384 + dk
    const int b    = flat >> 14;
    const int dk   = flat & 16383;

    if (side == 0) {
        float4 a = make_float4(0.f, 0.f, 0.f, 0.f);
#pragma unroll
        for (int sc = 0; sc < 8; ++sc) {
            float4 v = *(const float4*)(PpartK + ((size_t)sc * B_ + b) * (KP_ * D_) + dk);
            a.x += v.x; a.y += v.y; a.z += v.z; a.w += v.w;
        }
        const int k = dk >> 6, d = dk & 63;            // d % 4 == 0
        float be = E_b[k];
        a.x += be; a.y += be; a.z += be; a.w += be;
        short4 h, lo;
        h.x = f2bf(a.x); lo.x = f2bf(a.x - bf2f(h.x));
        h.y = f2bf(a.y); lo.y = f2bf(a.y - bf2f(h.y));
        h.z = f2bf(a.z); lo.z = f2bf(a.z - bf2f(h.z));
        h.w = f2bf(a.w); lo.w = f2bf(a.w - bf2f(h.w));
        const size_t fo = (((size_t)b * 2 + (d >> 5)) * 16 + (k >> 4)) * 512
                        + (size_t)((k & 15) + ((d >> 3) & 3) * 16) * 8 + (d & 7);
        *(short4*)(Kp_hi + fo) = h;
        *(short4*)(Kp_lo + fo) = lo;
    } else {
        float4 a = make_float4(0.f, 0.f, 0.f, 0.f);
#pragma unroll
        for (int sc = 0; sc < 8; ++sc) {
            float4 v = *(const float4*)(PpartV + ((size_t)sc * B_ + b) * (KP_ * D_) + dk);
            a.x += v.x; a.y += v.y; a.z += v.z; a.w += v.w;
        }
        const int d = dk >> 8, k = dk & 255;           // k % 4 == 0
        float4 bf = *(const float4*)(F_b + k);
        a.x += bf.x; a.y += bf.y; a.z += bf.z; a.w += bf.w;
        short4 h;
        h.x = f2bf(a.x); h.y = f2bf(a.y); h.z = f2bf(a.z); h.w = f2bf(a.w);
        const size_t fo = (((size_t)b * 8 + (k >> 5)) * 4 + (d >> 4)) * 512
                        + (size_t)((d & 15) + ((k >> 3) & 3) * 16) * 8 + (k & 7);
        *(short4*)(Vp_hi + fo) = h;
    }
}

// ---------------------------------------------------------------------------
// Kernel 4: scores -> softmax -> attn write -> out, all MFMA.
// grid (64 st, 16 b) x 256 thr (4 waves). LDS 50688 B, regions time-shared.
// R5: PV second half (kc4-7) restaged into KLh after kc0-3 consumed.
// ---------------------------------------------------------------------------
__global__ __launch_bounds__(256, 3)
void attn_mfma_kernel(const float* __restrict__ Qg,
                      const short* __restrict__ Kp_hi, const short* __restrict__ Kp_lo,
                      const short* __restrict__ Vp_hi,
                      float* __restrict__ attn_out, float* __restrict__ outg)
{
    const int st = blockIdx.x;
    const int b  = blockIdx.y;
    const int t  = threadIdx.x;
    const int wv = t >> 6;
    const int l  = t & 63;

    __shared__ __align__(16) short smem[64 * 264];     // union: Qf+KLl / Pl
    __shared__ __align__(16) float Fst[4][4][264];     // union: KLh / store staging / VL
    short (*Qf)[2][4][512] = (short (*)[2][4][512])smem;   // [kd][plane][mt][fraglane*8]
    short* Pl  = smem;                                 // attn tile, pitch 264
    short* KLl = smem + 8192;                          // 16KB lo-plane staging
    short* KLh = (short*)&Fst[0][0][0];                // 16KB hi-plane staging

    {   // stage Q fragments (hi/lo)
        const int s    = t & 63;
        const int doct = t >> 6;
        const float* qrow = Qg + ((size_t)b * S_ + st * 64 + s) * D_;
        const int mt = s >> 4, fl = (s & 15) + doct * 16;
#pragma unroll
        for (int kd = 0; kd < 2; ++kd) {
            float4 v0 = *(const float4*)(qrow + kd * 32 + doct * 8);
            float4 v1 = *(const float4*)(qrow + kd * 32 + doct * 8 + 4);
            float gq[8] = {v0.x, v0.y, v0.z, v0.w, v1.x, v1.y, v1.z, v1.w};
            v8s hi, lo;
#pragma unroll
            for (int jj = 0; jj < 8; ++jj) { short h = f2bf(gq[jj]); hi[jj] = h; lo[jj] = f2bf(gq[jj] - bf2f(h)); }
            *(v8s*)&Qf[kd][0][mt][fl * 8] = hi;
            *(v8s*)&Qf[kd][1][mt][fl * 8] = lo;
        }
    }
    __syncthreads();

    // scores: C2[16 s x 256 k], 3-term split; B-operands LDS-staged per kd
    v4f acc2[16];
#pragma unroll
    for (int nt = 0; nt < 16; ++nt) acc2[nt] = (v4f){0.f, 0.f, 0.f, 0.f};
#pragma unroll
    for (int kd = 0; kd < 2; ++kd) {
        {   // cooperative copy: Kp_hi[kd] -> KLh, Kp_lo[kd] -> KLl (16KB each)
            const size_t tbl = (((size_t)b * 2 + kd) * 16) * 512;   // shorts
            const int4* gh = (const int4*)(Kp_hi + tbl);
            const int4* gl = (const int4*)(Kp_lo + tbl);
            int4* lh = (int4*)KLh;
            int4* ll = (int4*)KLl;
#pragma unroll
            for (int i = 0; i < 4; ++i) lh[t + i * 256] = gh[t + i * 256];
#pragma unroll
            for (int i = 0; i < 4; ++i) ll[t + i * 256] = gl[t + i * 256];
        }
        __syncthreads();
        v8s Ah = *(const v8s*)&Qf[kd][0][wv][l * 8];
        v8s Al = *(const v8s*)&Qf[kd][1][wv][l * 8];
#pragma unroll
        for (int nt = 0; nt < 16; ++nt) {
            v8s Bh = *(const v8s*)&KLh[nt * 512 + l * 8];
            v8s Bl = *(const v8s*)&KLl[nt * 512 + l * 8];
            acc2[nt] = __builtin_amdgcn_mfma_f32_16x16x32_bf16(Ah, Bh, acc2[nt], 0, 0, 0);
            acc2[nt] = __builtin_amdgcn_mfma_f32_16x16x32_bf16(Al, Bh, acc2[nt], 0, 0, 0);
            acc2[nt] = __builtin_amdgcn_mfma_f32_16x16x32_bf16(Ah, Bl, acc2[nt], 0, 0, 0);
        }
        __syncthreads();   // staging buffers reusable (next kd / Pl / Fst)
    }

    // softmax per row (C layout: row = wv*16 + (l>>4)*4 + r, col = nt*16 + (l&15))
    const float scale = 0.125f;   // 1/sqrt(64)
    float* attn_b = attn_out + ((size_t)b * S_ + st * 64) * KP_;
    const int g = l >> 4;
#pragma unroll
    for (int r = 0; r < 4; ++r) {
        float m = -3.4e38f;
#pragma unroll
        for (int nt = 0; nt < 16; ++nt) m = fmaxf(m, acc2[nt][r]);
        m = fmaxf(m, __shfl_xor(m, 1));
        m = fmaxf(m, __shfl_xor(m, 2));
        m = fmaxf(m, __shfl_xor(m, 4));
        m = fmaxf(m, __shfl_xor(m, 8));
        float sum = 0.f;
#pragma unroll
        for (int nt = 0; nt < 16; ++nt) {
            float e = __expf((acc2[nt][r] - m) * scale);
            acc2[nt][r] = e; sum += e;
        }
        sum += __shfl_xor(sum, 1);
        sum += __shfl_xor(sum, 2);
        sum += __shfl_xor(sum, 4);
        sum += __shfl_xor(sum, 8);
        const float inv = 1.f / sum;
        const int s_loc = wv * 16 + g * 4 + r;
#pragma unroll
        for (int nt = 0; nt < 16; ++nt) {
            float pv = acc2[nt][r] * inv;
            Fst[wv][g][nt * 16 + (l & 15)] = pv;               // f32 for coalesced store
            Pl[s_loc * 264 + nt * 16 + (l & 15)] = f2bf(pv);   // bf16 for PV
        }
        // coalesced attn store: one dense 1KB row per instr (same-wave LDS RAW)
#pragma unroll
        for (int gg = 0; gg < 4; ++gg) {
            float4 vv = *(const float4*)&Fst[wv][gg][l * 4];
            *(float4*)(attn_b + (size_t)(wv * 16 + gg * 4 + r) * KP_ + l * 4) = vv;
        }
    }
    // stage Vp kc0-3 (16KB) into Fst region (dead after attn stores)
    __syncthreads();
    {
        const int4* gv = (const int4*)(Vp_hi + (size_t)b * 16384);
        int4* lv = (int4*)KLh;
#pragma unroll
        for (int i = 0; i < 4; ++i) lv[t + i * 256] = gv[t + i * 256];
    }
    __syncthreads();
    // PV: rows wv*16..+16 of Pl written by this wave only
    v4f acc3[4];
#pragma unroll
    for (int nt = 0; nt < 4; ++nt) acc3[nt] = (v4f){0.f, 0.f, 0.f, 0.f};
#pragma unroll
    for (int kc = 0; kc < 4; ++kc) {
        v8s A3 = *(const v8s*)&Pl[(wv * 16 + (l & 15)) * 264 + kc * 32 + (l >> 4) * 8];
#pragma unroll
        for (int nt = 0; nt < 4; ++nt) {
            v8s B3 = *(const v8s*)&KLh[(kc * 4 + nt) * 512 + l * 8];
            acc3[nt] = __builtin_amdgcn_mfma_f32_16x16x32_bf16(A3, B3, acc3[nt], 0, 0, 0);
        }
    }
    // restage Vp kc4-7 into the same buffer
    __syncthreads();
    {
        const int4* gv = (const int4*)(Vp_hi + (size_t)b * 16384 + 8192);
        int4* lv = (int4*)KLh;
#pragma unroll
        for (int i = 0; i < 4; ++i) lv[t + i * 256] = gv[t + i * 256];
    }
    __syncthreads();
#pragma unroll
    for (int kc = 4; kc < 8; ++kc) {
        v8s A3 = *(const v8s*)&Pl[(wv * 16 + (l & 15)) * 264 + kc * 32 + (l >> 4) * 8];
#pragma unroll
        for (int nt = 0; nt < 4; ++nt) {
            v8s B3 = *(const v8s*)&KLh[((kc - 4) * 4 + nt) * 512 + l * 8];
            acc3[nt] = __builtin_amdgcn_mfma_f32_16x16x32_bf16(A3, B3, acc3[nt], 0, 0, 0);
        }
    }
    float* out_b = outg + ((size_t)b * S_ + st * 64) * D_;
#pragma unroll
    for (int nt = 0; nt < 4; ++nt)
#pragma unroll
        for (int r = 0; r < 4; ++r) {
            int s_loc = wv * 16 + (l >> 4) * 4 + r;
            out_b[(size_t)s_loc * D_ + nt * 16 + (l & 15)] = acc3[nt][r];
        }
}

extern "C" void kernel_launch(void* const* d_in, const int* in_sizes, int n_in,
                              void* d_out, int out_size, void* d_ws, size_t ws_size,
                              hipStream_t stream) {
    const float* Q   = (const float*)d_in[0];
    const float* K   = (const float*)d_in[1];
    const float* V   = (const float*)d_in[2];
    const float* E_w = (const float*)d_in[3];
    const float* E_b = (const float*)d_in[4];
    const float* F_w = (const float*)d_in[5];
    const float* F_b = (const float*)d_in[6];

    float* out  = (float*)d_out;                        // [B,S,D]
    float* attn = out + (size_t)B_ * S_ * D_;           // [B,S,KP]

    // ws: bf16 planes (9.5 MB total)
    short* Whi   = (short*)d_ws;                        // [2][KP][S] frag-tile, 4 MB
    short* Wlo   = Whi + (size_t)2 * KP_ * S_;          // 4 MB
    short* Kp_hi = Wlo + (size_t)2 * KP_ * S_;          // frag-order, 512 KB
    short* Kp_lo = Kp_hi + (size_t)B_ * KP_ * D_;
    short* Vp_hi = Kp_lo + (size_t)B_ * KP_ * D_;       // frag-order

    // partials live in the attn output region (dead until attn_mfma_kernel)
    float* PpartK = attn;                               // [8][B][KP*D]  8 MB
    float* PpartV = attn + (size_t)8 * B_ * KP_ * D_;   // [8][B][KP*D]  8 MB

    wcvt_kernel<<<dim3(KP_ * S_ / 4 / 256, 2), 256, 0, stream>>>(E_w, F_w, Whi, Wlo);
    proj_mfma_kernel<<<dim3(8, 2, B_), 512, 0, stream>>>(K, V, Whi, Wlo, PpartK, PpartV);
    reduce_kernel<<<dim3(512), 256, 0, stream>>>(PpartK, PpartV, E_b, F_b, Kp_hi, Kp_lo, Vp_hi);
    attn_mfma_kernel<<<dim3(S_ / 64, B_), 256, 0, stream>>>(Q, Kp_hi, Kp_lo, Vp_hi, attn, out);
}